// Round 16
// baseline (253.426 us; speedup 1.0000x reference)
//
#include <hip/hip_runtime.h>
#include <hip/hip_bf16.h>
#include <stdint.h>

#define DIMM 1024
#define HEADS 16
#define HD 64
#define BB 2
#define SS 2048
#define NTOK (BB*SS)

typedef __attribute__((ext_vector_type(8))) __bf16 bf16x8;
typedef __attribute__((ext_vector_type(4))) __bf16 bf16x4;
typedef __attribute__((ext_vector_type(4))) float f32x4;

__device__ __forceinline__ f32x4 mfma16(bf16x8 a, bf16x8 b, f32x4 c) {
  return __builtin_amdgcn_mfma_f32_16x16x32_bf16(a, b, c, 0, 0, 0);
}

__device__ __forceinline__ void gload_lds16(const void* g, void* l) {
  __builtin_amdgcn_global_load_lds(
      (__attribute__((address_space(1))) void*)(void*)g,
      (__attribute__((address_space(3))) void*)l,
      16, 0, 0);
}

#define LOG2E 1.4426950408889634f
#define C2 (0.125f * LOG2E)      /* score scale folded into log2 domain */
#define NBRAW (-8e9f)            /* raw-domain masked score: -8e9*0.125 = -1e9 */

// ---------------- convert fp32 -> bf16 (weights only) + maskbits ----------------
struct CvtArgs {
  const float* src[4];
  __bf16* dst[4];
  int n[4];
  const int* msk;
  uint32_t* mbits;
};

__global__ __launch_bounds__(256) void cvt_kernel(CvtArgs a) {
  const int t = blockIdx.y;
  if (t == 4) {
    // maskbits: 128 words [b][k>>5], only block x==0 works
    if (blockIdx.x == 0 && threadIdx.x < 128) {
      const int* src = a.msk + threadIdx.x * 32;
      uint32_t wdd = 0;
#pragma unroll
      for (int i = 0; i < 32; ++i) wdd |= (src[i] != 0 ? 1u : 0u) << i;
      a.mbits[threadIdx.x] = wdd;
    }
    return;
  }
  const long i = ((long)blockIdx.x * 256 + threadIdx.x) * 8;
  if (i >= a.n[t]) return;
  const float* s = a.src[t] + i;
  f32x4 x0 = *(const f32x4*)s;
  f32x4 x1 = *(const f32x4*)(s + 4);
  bf16x8 o;
  o[0] = (__bf16)x0[0]; o[1] = (__bf16)x0[1]; o[2] = (__bf16)x0[2]; o[3] = (__bf16)x0[3];
  o[4] = (__bf16)x1[0]; o[5] = (__bf16)x1[1]; o[6] = (__bf16)x1[2]; o[7] = (__bf16)x1[3];
  *(bf16x8*)(a.dst[t] + i) = o;
}

// ---------------- GEMM: C[m,n] = sum_k A[m,k]*B[n,k] + bias[n] ----------------
// If Af[z] != null, A is fp32 and converted in-staging (fused cvt, T14 split:
// f32 loads issued before the MFMA phase, cvt+ds_write after).
struct GemmArgs {
  const __bf16* A[3];
  const float* Af[3];
  const __bf16* B[3];
  const float* bias[3];
  void* out[3];
  int mode[3];
};

__global__ __launch_bounds__(256) void gemm_bt(GemmArgs ga) {
  const int z = blockIdx.z;
  const __bf16* __restrict__ A  = ga.A[z];
  const float* __restrict__ Af  = ga.Af[z];
  const __bf16* __restrict__ Bm = ga.B[z];
  const float* __restrict__ bias = ga.bias[z];
  void* Cout = ga.out[z];
  const int mode = ga.mode[z];

  __shared__ __align__(16) char sA[2][16384];
  __shared__ __align__(16) char sB[2][16384];
  const int tid = threadIdx.x;
  const int w = tid >> 6, l = tid & 63;
  const int wr = w >> 1, wc = w & 1;
  const int lg = l >> 4, lr = l & 15;
  const int m0 = blockIdx.y * 128, n0 = blockIdx.x * 128;

  f32x4 acc[4][4] = {};

  auto stageA_g = [&](int k0, int buf) {
#pragma unroll
    for (int i = 0; i < 4; ++i) {
      int c = (i * 4 + w) * 64 + l;
      int row = c >> 3, ch = c & 7;
      gload_lds16(A + (size_t)(m0 + row) * 1024 + k0 + ((ch ^ (row & 7)) << 3),
                  &sA[buf][(i * 4 + w) * 1024]);
    }
  };
  auto stageB = [&](int k0, int buf) {
#pragma unroll
    for (int i = 0; i < 4; ++i) {
      int c = (i * 4 + w) * 64 + l;
      int row = c >> 3, ch = c & 7;
      gload_lds16(Bm + (size_t)(n0 + row) * 1024 + k0 + ((ch ^ (row & 7)) << 3),
                  &sB[buf][(i * 4 + w) * 1024]);
    }
  };

  // prologue: stage tile 0
  if (Af) {
#pragma unroll
    for (int i = 0; i < 4; ++i) {
      int c = (i * 4 + w) * 64 + l;
      int row = c >> 3, ch = c & 7;
      const float* src = Af + (size_t)(m0 + row) * 1024 + ((ch ^ (row & 7)) << 3);
      f32x4 x0 = *(const f32x4*)src;
      f32x4 x1 = *(const f32x4*)(src + 4);
      bf16x8 o;
#pragma unroll
      for (int r = 0; r < 4; ++r) { o[r] = (__bf16)x0[r]; o[4 + r] = (__bf16)x1[r]; }
      *(bf16x8*)&sA[0][c * 16] = o;
    }
  } else {
    stageA_g(0, 0);
  }
  stageB(0, 0);
  __syncthreads();

  for (int ks = 0; ks < 16; ++ks) {
    const int cur = ks & 1;
    // fused path: issue next-tile fp32 A loads BEFORE compute (latency hides)
    f32x4 a0_[4], a1_[4];
    if (Af && ks < 15) {
#pragma unroll
      for (int i = 0; i < 4; ++i) {
        int c = (i * 4 + w) * 64 + l;
        int row = c >> 3, ch = c & 7;
        const float* src = Af + (size_t)(m0 + row) * 1024 + (ks + 1) * 64 +
                           ((ch ^ (row & 7)) << 3);
        a0_[i] = *(const f32x4*)src;
        a1_[i] = *(const f32x4*)(src + 4);
      }
    }
    if (!Af && ks < 15) stageA_g((ks + 1) * 64, cur ^ 1);
    if (ks < 15) stageB((ks + 1) * 64, cur ^ 1);

#pragma unroll
    for (int kk = 0; kk < 2; ++kk) {
      bf16x8 af[4], bfv[4];
#pragma unroll
      for (int fm = 0; fm < 4; ++fm) {
        int row = wr * 64 + fm * 16 + lr;
        af[fm] = *(const bf16x8*)&sA[cur][row * 128 + (((kk * 4 + lg) ^ (row & 7)) << 4)];
      }
#pragma unroll
      for (int fn = 0; fn < 4; ++fn) {
        int row = wc * 64 + fn * 16 + lr;
        bfv[fn] = *(const bf16x8*)&sB[cur][row * 128 + (((kk * 4 + lg) ^ (row & 7)) << 4)];
      }
#pragma unroll
      for (int fm = 0; fm < 4; ++fm)
#pragma unroll
        for (int fn = 0; fn < 4; ++fn)
          acc[fm][fn] = mfma16(af[fm], bfv[fn], acc[fm][fn]);
    }

    if (Af && ks < 15) {
      // cvt + write next A-tile into the other buffer (no one reads it now)
#pragma unroll
      for (int i = 0; i < 4; ++i) {
        int c = (i * 4 + w) * 64 + l;
        bf16x8 o;
#pragma unroll
        for (int r = 0; r < 4; ++r) { o[r] = (__bf16)a0_[i][r]; o[4 + r] = (__bf16)a1_[i][r]; }
        *(bf16x8*)&sA[cur ^ 1][c * 16] = o;
      }
    }
    __syncthreads();
  }

#pragma unroll
  for (int fm = 0; fm < 4; ++fm) {
#pragma unroll
    for (int fn = 0; fn < 4; ++fn) {
      const int n = n0 + wc * 64 + fn * 16 + lr;
      const int mb = m0 + wr * 64 + fm * 16 + 4 * lg;
      const float bval = bias[n];
      f32x4 vv = acc[fm][fn];
      if (mode == 2) {
        float* C = (float*)Cout;
#pragma unroll
        for (int r = 0; r < 4; ++r)
          C[(size_t)(mb + r) * 1024 + n] = vv[r] + bval;
      } else if (mode == 0) {
        __bf16* C = (__bf16*)Cout;
        const int hh = n >> 6, d = n & 63;
#pragma unroll
        for (int r = 0; r < 4; ++r) {
          int m = mb + r;
          C[(((size_t)(m >> 11) * 16 + hh) * 2048 + (m & 2047)) * 64 + d] =
              (__bf16)(vv[r] + bval);
        }
      } else {
        __bf16* C = (__bf16*)Cout;
        const int hh = n >> 6, d = n & 63;
        bf16x4 pk;
#pragma unroll
        for (int r = 0; r < 4; ++r) pk[r] = (__bf16)(vv[r] + bval);
        *(bf16x4*)(C + (((size_t)(mb >> 11) * 16 + hh) * 64 + d) * 2048 + (mb & 2047)) = pk;
      }
    }
  }
}

// ---------------- fused attention (R15-best, unchanged) ----------------
__global__ __launch_bounds__(256) void attn_kernel(
    const __bf16* __restrict__ Qh, const __bf16* __restrict__ Kh,
    const __bf16* __restrict__ Vt, const uint32_t* __restrict__ mbits,
    float* __restrict__ attnW, __bf16* __restrict__ ctx)
{
  __shared__ __align__(16) char sK[2][8192];
  __shared__ __align__(16) char sV[2][8192];
  __shared__ __align__(16) __bf16 sPB[4][16][64];   // wave-private P, bf16

  const int tid = threadIdx.x;
  const int w = tid >> 6, l = tid & 63;
  const int lg = l >> 4, lr = l & 15;

  const int bid = blockIdx.x;
  const int xcd = bid & 7, j = bid >> 3;
  const int bh = xcd * 4 + (j >> 5);      // each head pinned to one XCD
  const int q0 = (j & 31) * 64;
  const int b = bh >> 4, h = bh & 15;

  const __bf16* qbase = Qh + ((size_t)bh * SS + q0 + w * 16 + lr) * HD;
  bf16x8 qf0 = *(const bf16x8*)(qbase + lg * 8);
  bf16x8 qf1 = *(const bf16x8*)(qbase + 32 + lg * 8);

  const __bf16* Khead = Kh + (size_t)bh * SS * HD;
  const __bf16* Vhead = Vt + (size_t)bh * HD * SS;
  const uint32_t* mrow = mbits + b * 64;

  const int c0 = w * 64 + l;

  auto stageK = [&](int k0, int buf) {
#pragma unroll
    for (int i = 0; i < 2; ++i) {
      int c = i * 256 + c0;
      int kr = c >> 3, ch = c & 7;
      gload_lds16(Khead + (size_t)(k0 + kr) * HD + ((ch ^ (kr & 7)) << 3),
                  &sK[buf][(i * 4 + w) * 1024]);
    }
  };
  auto stageV = [&](int k0, int buf) {
#pragma unroll
    for (int i = 0; i < 2; ++i) {
      int c = i * 256 + c0;
      int d = c >> 3, ch = c & 7;
      gload_lds16(Vhead + (size_t)d * SS + k0 + ((ch ^ (d & 7)) << 3),
                  &sV[buf][(i * 4 + w) * 1024]);
    }
  };

  // ---- pass 1: per-row sumexp (max-free, clamped). lane q = lr, k = 4lg+r ----
  stageK(0, 0);
  asm volatile("s_waitcnt vmcnt(0)" ::: "memory");
  __builtin_amdgcn_s_barrier();

  float lsum = 0.0f;

  for (int t = 0; t < 32; ++t) {
    const int cur = t & 1;
    if (t < 31) stageK((t + 1) * 64, cur ^ 1);

    const uint32_t mw0 = mrow[2 * t], mw1 = mrow[2 * t + 1];
    const bool fast = ((mw0 & mw1) == 0xFFFFFFFFu);

#pragma unroll
    for (int sub = 0; sub < 4; ++sub) {
      const int kr = sub * 16 + lr;
      bf16x8 k0f = *(const bf16x8*)&sK[cur][kr * 128 + ((lg ^ (kr & 7)) << 4)];
      bf16x8 k1f = *(const bf16x8*)&sK[cur][kr * 128 + (((4 + lg) ^ (kr & 7)) << 4)];
      __builtin_amdgcn_s_setprio(1);
      f32x4 a = {};
      a = mfma16(k0f, qf0, a);
      a = mfma16(k1f, qf1, a);
      __builtin_amdgcn_s_setprio(0);
      if (!fast) {
        uint32_t bits = ((sub < 2) ? mw0 : mw1) >> ((sub & 1) * 16 + 4 * lg);
#pragma unroll
        for (int r = 0; r < 4; ++r) a[r] = ((bits >> r) & 1) ? a[r] : NBRAW;
      }
#pragma unroll
      for (int r = 0; r < 4; ++r)
        lsum += __builtin_amdgcn_exp2f(fminf(a[r] * C2, 80.0f));
    }
    asm volatile("s_waitcnt vmcnt(0)" ::: "memory");
    __builtin_amdgcn_s_barrier();
  }

  lsum += __shfl_xor(lsum, 16);
  lsum += __shfl_xor(lsum, 32);
  const float rl = 1.0f / lsum;

  f32x4 Oa[4] = {};
  float* pwbase = attnW + ((size_t)bh * SS + q0 + w * 16) * SS;

  // ---- pass 2: P(bf16) via LDS-transpose + 256B-run NT store + PV ----
  stageK(0, 0);
  stageV(0, 0);
  asm volatile("s_waitcnt vmcnt(0)" ::: "memory");
  __builtin_amdgcn_s_barrier();

  for (int t = 0; t < 32; ++t) {
    const int cur = t & 1;
    if (t < 31) { stageK((t + 1) * 64, cur ^ 1); stageV((t + 1) * 64, cur ^ 1); }

    const uint32_t mw0 = mrow[2 * t], mw1 = mrow[2 * t + 1];
    const bool fast = ((mw0 & mw1) == 0xFFFFFFFFu);

#pragma unroll
    for (int sub = 0; sub < 4; ++sub) {
      const int kr = sub * 16 + lr;
      bf16x8 k0f = *(const bf16x8*)&sK[cur][kr * 128 + ((lg ^ (kr & 7)) << 4)];
      bf16x8 k1f = *(const bf16x8*)&sK[cur][kr * 128 + (((4 + lg) ^ (kr & 7)) << 4)];
      __builtin_amdgcn_s_setprio(1);
      f32x4 a = {};
      a = mfma16(k0f, qf0, a);
      a = mfma16(k1f, qf1, a);
      __builtin_amdgcn_s_setprio(0);
      if (!fast) {
        uint32_t bits = ((sub < 2) ? mw0 : mw1) >> ((sub & 1) * 16 + 4 * lg);
#pragma unroll
        for (int r = 0; r < 4; ++r) a[r] = ((bits >> r) & 1) ? a[r] : NBRAW;
      }
      bf16x4 pk;
#pragma unroll
      for (int r = 0; r < 4; ++r)
        pk[r] = (__bf16)(__builtin_amdgcn_exp2f(fminf(a[r] * C2, 80.0f)) * rl);
      const int cc = ((sub * 2 + (lg >> 1)) ^ (lr & 7));
      *(bf16x4*)((char*)&sPB[w][lr][0] + cc * 16 + (lg & 1) * 8) = pk;
    }

    // -- transposed NT store: 4 instrs x (4 rows x 256B contiguous runs) --
#pragma unroll
    for (int i = 0; i < 4; ++i) {
      const int row = i * 4 + (l >> 4);
      const int jj = l & 15;
      const int cc = (jj >> 1) ^ (row & 7);
      bf16x4 pb = *(const bf16x4*)((const char*)&sPB[w][row][0] + cc * 16 + (jj & 1) * 8);
      f32x4 pv;
#pragma unroll
      for (int r = 0; r < 4; ++r) pv[r] = (float)pb[r];
      __builtin_nontemporal_store(pv,
          (f32x4*)(pwbase + (size_t)row * SS + t * 64 + jj * 4));
    }

    // -- PV: A-operand bf16x8 direct from sPB --
#pragma unroll
    for (int hh = 0; hh < 2; ++hh) {
      bf16x8 pa = *(const bf16x8*)((const char*)&sPB[w][lr][0] +
                                   (((hh * 4 + lg) ^ (lr & 7)) * 16));
      __builtin_amdgcn_s_setprio(1);
#pragma unroll
      for (int dg = 0; dg < 4; ++dg) {
        const int d = dg * 16 + lr;
        bf16x8 vb = *(const bf16x8*)&sV[cur][d * 128 + (((hh * 4 + lg) ^ (d & 7)) << 4)];
        Oa[dg] = mfma16(pa, vb, Oa[dg]);
      }
      __builtin_amdgcn_s_setprio(0);
    }

    asm volatile("s_waitcnt vmcnt(4)" ::: "memory");
    __builtin_amdgcn_s_barrier();
  }

  // epilogue: context -> [b*s][h*64+d] bf16 (Oa: q = 4lg+r, d = dg*16+lr)
#pragma unroll
  for (int dg = 0; dg < 4; ++dg)
#pragma unroll
    for (int r = 0; r < 4; ++r)
      ctx[(size_t)(b * SS + q0 + w * 16 + 4 * lg + r) * DIMM + h * HD + dg * 16 + lr] =
          (__bf16)Oa[dg][r];
}

// ---------------- launch ----------------
extern "C" void kernel_launch(void* const* d_in, const int* in_sizes, int n_in,
                              void* d_out, int out_size, void* d_ws, size_t ws_size,
                              hipStream_t stream)
{
  const float* q   = (const float*)d_in[0];
  const float* k   = (const float*)d_in[1];
  const float* v   = (const float*)d_in[2];
  const int*   msk = (const int*)d_in[3];
  const float* Wq  = (const float*)d_in[4];
  const float* bq  = (const float*)d_in[5];
  const float* Wk  = (const float*)d_in[6];
  const float* bk  = (const float*)d_in[7];
  const float* Wv  = (const float*)d_in[8];
  const float* bv  = (const float*)d_in[9];
  const float* Wo  = (const float*)d_in[10];
  const float* bo  = (const float*)d_in[11];

  char* ws = (char*)d_ws;
  __bf16* wqb = (__bf16*)(ws + (24u << 20));
  __bf16* wkb = (__bf16*)(ws + (26u << 20));
  __bf16* wvb = (__bf16*)(ws + (28u << 20));
  __bf16* wob = (__bf16*)(ws + (30u << 20));
  __bf16* Qh  = (__bf16*)(ws + (32u << 20));
  __bf16* Kh  = (__bf16*)(ws + (40u << 20));
  __bf16* Vt  = (__bf16*)(ws + (48u << 20));
  __bf16* ctx = (__bf16*)(ws + (56u << 20));
  uint32_t* mbits = (uint32_t*)(ws + (64u << 20));

  CvtArgs ca;
  ca.src[0] = Wq; ca.dst[0] = wqb; ca.n[0] = DIMM * DIMM;
  ca.src[1] = Wk; ca.dst[1] = wkb; ca.n[1] = DIMM * DIMM;
  ca.src[2] = Wv; ca.dst[2] = wvb; ca.n[2] = DIMM * DIMM;
  ca.src[3] = Wo; ca.dst[3] = wob; ca.n[3] = DIMM * DIMM;
  ca.msk = msk; ca.mbits = mbits;
  cvt_kernel<<<dim3(512, 5, 1), 256, 0, stream>>>(ca);

  GemmArgs g1;
  g1.A[0] = nullptr; g1.Af[0] = q; g1.B[0] = wqb; g1.bias[0] = bq; g1.out[0] = (void*)Qh; g1.mode[0] = 0;
  g1.A[1] = nullptr; g1.Af[1] = k; g1.B[1] = wkb; g1.bias[1] = bk; g1.out[1] = (void*)Kh; g1.mode[1] = 0;
  g1.A[2] = nullptr; g1.Af[2] = v; g1.B[2] = wvb; g1.bias[2] = bv; g1.out[2] = (void*)Vt; g1.mode[2] = 1;
  gemm_bt<<<dim3(8, 32, 3), 256, 0, stream>>>(g1);

  float* out = (float*)d_out;
  float* attnW = out + (size_t)NTOK * DIMM;
  attn_kernel<<<dim3(1024, 1, 1), 256, 0, stream>>>(Qh, Kh, Vt, mbits, attnW, ctx);

  GemmArgs g2;
  g2.A[0] = ctx; g2.Af[0] = nullptr; g2.B[0] = wob; g2.bias[0] = bo; g2.out[0] = (void*)out; g2.mode[0] = 2;
  g2.A[1] = ctx; g2.Af[1] = nullptr; g2.B[1] = wob; g2.bias[1] = bo; g2.out[1] = (void*)out; g2.mode[1] = 2;
  g2.A[2] = ctx; g2.Af[2] = nullptr; g2.B[2] = wob; g2.bias[2] = bo; g2.out[2] = (void*)out; g2.mode[2] = 2;
  gemm_bt<<<dim3(8, 32, 1), 256, 0, stream>>>(g2);
}

// Round 17
// 244.391 us; speedup vs baseline: 1.0370x; 1.0370x over previous
//
#include <hip/hip_runtime.h>
#include <hip/hip_bf16.h>
#include <stdint.h>

#define DIMM 1024
#define HEADS 16
#define HD 64
#define BB 2
#define SS 2048
#define NTOK (BB*SS)

typedef __attribute__((ext_vector_type(8))) __bf16 bf16x8;
typedef __attribute__((ext_vector_type(4))) __bf16 bf16x4;
typedef __attribute__((ext_vector_type(4))) float f32x4;

__device__ __forceinline__ f32x4 mfma16(bf16x8 a, bf16x8 b, f32x4 c) {
  return __builtin_amdgcn_mfma_f32_16x16x32_bf16(a, b, c, 0, 0, 0);
}

__device__ __forceinline__ void gload_lds16(const void* g, void* l) {
  __builtin_amdgcn_global_load_lds(
      (__attribute__((address_space(1))) void*)(void*)g,
      (__attribute__((address_space(3))) void*)l,
      16, 0, 0);
}

#define LOG2E 1.4426950408889634f
#define C2 (0.125f * LOG2E)      /* score scale folded into log2 domain */
#define NBRAW (-8e9f)            /* raw-domain masked score: -8e9*0.125 = -1e9 */

// ---------------- convert fp32 -> bf16 ----------------
struct CvtArgs {
  const float* src[7];
  __bf16* dst[7];
  int n[7];
};

__global__ __launch_bounds__(256) void cvt_kernel(CvtArgs a) {
  const int t = blockIdx.y;
  const long i = ((long)blockIdx.x * 256 + threadIdx.x) * 8;
  if (i >= a.n[t]) return;
  const float* s = a.src[t] + i;
  f32x4 x0 = *(const f32x4*)s;
  f32x4 x1 = *(const f32x4*)(s + 4);
  bf16x8 o;
  o[0] = (__bf16)x0[0]; o[1] = (__bf16)x0[1]; o[2] = (__bf16)x0[2]; o[3] = (__bf16)x0[3];
  o[4] = (__bf16)x1[0]; o[5] = (__bf16)x1[1]; o[6] = (__bf16)x1[2]; o[7] = (__bf16)x1[3];
  *(bf16x8*)(a.dst[t] + i) = o;
}

// ---------------- mask -> bitmask (128 words: [b][k>>5]) ----------------
__global__ void maskbits_kernel(const int* __restrict__ msk, uint32_t* __restrict__ mbits) {
  int j = threadIdx.x;
  if (j >= 128) return;
  const int* src = msk + j * 32;
  uint32_t wdd = 0;
#pragma unroll
  for (int i = 0; i < 32; ++i) wdd |= (src[i] != 0 ? 1u : 0u) << i;
  mbits[j] = wdd;
}

// ---------------- GEMM: C[m,n] = sum_k A[m,k]*B[n,k] + bias[n] ----------------
struct GemmArgs {
  const __bf16* A[3];
  const __bf16* B[3];
  const float* bias[3];
  void* out[3];
  int mode[3];
};

__global__ __launch_bounds__(256) void gemm_bt(GemmArgs ga) {
  const int z = blockIdx.z;
  const __bf16* __restrict__ A  = ga.A[z];
  const __bf16* __restrict__ Bm = ga.B[z];
  const float* __restrict__ bias = ga.bias[z];
  void* Cout = ga.out[z];
  const int mode = ga.mode[z];

  __shared__ __align__(16) char sA[2][16384];
  __shared__ __align__(16) char sB[2][16384];
  const int tid = threadIdx.x;
  const int w = tid >> 6, l = tid & 63;
  const int wr = w >> 1, wc = w & 1;
  const int lg = l >> 4, lr = l & 15;
  const int m0 = blockIdx.y * 128, n0 = blockIdx.x * 128;

  f32x4 acc[4][4] = {};

  auto stage = [&](int k0, int buf) {
#pragma unroll
    for (int i = 0; i < 4; ++i) {
      int c = (i * 4 + w) * 64 + l;
      int row = c >> 3, ch = c & 7;
      gload_lds16(A + (size_t)(m0 + row) * 1024 + k0 + ((ch ^ (row & 7)) << 3),
                  &sA[buf][(i * 4 + w) * 1024]);
    }
#pragma unroll
    for (int i = 0; i < 4; ++i) {
      int c = (i * 4 + w) * 64 + l;
      int row = c >> 3, ch = c & 7;
      gload_lds16(Bm + (size_t)(n0 + row) * 1024 + k0 + ((ch ^ (row & 7)) << 3),
                  &sB[buf][(i * 4 + w) * 1024]);
    }
  };

  stage(0, 0);
  __syncthreads();

  for (int ks = 0; ks < 16; ++ks) {
    const int cur = ks & 1;
    if (ks < 15) stage((ks + 1) * 64, cur ^ 1);
#pragma unroll
    for (int kk = 0; kk < 2; ++kk) {
      bf16x8 af[4], bfv[4];
#pragma unroll
      for (int fm = 0; fm < 4; ++fm) {
        int row = wr * 64 + fm * 16 + lr;
        af[fm] = *(const bf16x8*)&sA[cur][row * 128 + (((kk * 4 + lg) ^ (row & 7)) << 4)];
      }
#pragma unroll
      for (int fn = 0; fn < 4; ++fn) {
        int row = wc * 64 + fn * 16 + lr;
        bfv[fn] = *(const bf16x8*)&sB[cur][row * 128 + (((kk * 4 + lg) ^ (row & 7)) << 4)];
      }
#pragma unroll
      for (int fm = 0; fm < 4; ++fm)
#pragma unroll
        for (int fn = 0; fn < 4; ++fn)
          acc[fm][fn] = mfma16(af[fm], bfv[fn], acc[fm][fn]);
    }
    __syncthreads();
  }

#pragma unroll
  for (int fm = 0; fm < 4; ++fm) {
#pragma unroll
    for (int fn = 0; fn < 4; ++fn) {
      const int n = n0 + wc * 64 + fn * 16 + lr;
      const int mb = m0 + wr * 64 + fm * 16 + 4 * lg;
      const float bval = bias[n];
      f32x4 vv = acc[fm][fn];
      if (mode == 2) {
        float* C = (float*)Cout;
#pragma unroll
        for (int r = 0; r < 4; ++r)
          C[(size_t)(mb + r) * 1024 + n] = vv[r] + bval;
      } else if (mode == 0) {
        __bf16* C = (__bf16*)Cout;
        const int hh = n >> 6, d = n & 63;
#pragma unroll
        for (int r = 0; r < 4; ++r) {
          int m = mb + r;
          C[(((size_t)(m >> 11) * 16 + hh) * 2048 + (m & 2047)) * 64 + d] =
              (__bf16)(vv[r] + bval);
        }
      } else {
        __bf16* C = (__bf16*)Cout;
        const int hh = n >> 6, d = n & 63;
        bf16x4 pk;
#pragma unroll
        for (int r = 0; r < 4; ++r) pk[r] = (__bf16)(vv[r] + bval);
        *(bf16x4*)(C + (((size_t)(mb >> 11) * 16 + hh) * 64 + d) * 2048 + (mb & 2047)) = pk;
      }
    }
  }
}

// ---------------- fused attention (R15-best) ----------------
// R9 structure with P buffered as bf16 over the FULL 64-col iter
// (sPB[4][16][64] bf16 = 8KB, LDS total 40KB -> 4 blocks/CU); NT store
// phase emits 4 instrs x 4 rows x 256B contiguous runs.
__global__ __launch_bounds__(256) void attn_kernel(
    const __bf16* __restrict__ Qh, const __bf16* __restrict__ Kh,
    const __bf16* __restrict__ Vt, const uint32_t* __restrict__ mbits,
    float* __restrict__ attnW, __bf16* __restrict__ ctx)
{
  __shared__ __align__(16) char sK[2][8192];
  __shared__ __align__(16) char sV[2][8192];
  __shared__ __align__(16) __bf16 sPB[4][16][64];   // wave-private P, bf16

  const int tid = threadIdx.x;
  const int w = tid >> 6, l = tid & 63;
  const int lg = l >> 4, lr = l & 15;

  const int bid = blockIdx.x;
  const int xcd = bid & 7, j = bid >> 3;
  const int bh = xcd * 4 + (j >> 5);      // each head pinned to one XCD
  const int q0 = (j & 31) * 64;
  const int b = bh >> 4, h = bh & 15;

  const __bf16* qbase = Qh + ((size_t)bh * SS + q0 + w * 16 + lr) * HD;
  bf16x8 qf0 = *(const bf16x8*)(qbase + lg * 8);
  bf16x8 qf1 = *(const bf16x8*)(qbase + 32 + lg * 8);

  const __bf16* Khead = Kh + (size_t)bh * SS * HD;
  const __bf16* Vhead = Vt + (size_t)bh * HD * SS;
  const uint32_t* mrow = mbits + b * 64;

  const int c0 = w * 64 + l;

  auto stageK = [&](int k0, int buf) {
#pragma unroll
    for (int i = 0; i < 2; ++i) {
      int c = i * 256 + c0;
      int kr = c >> 3, ch = c & 7;
      gload_lds16(Khead + (size_t)(k0 + kr) * HD + ((ch ^ (kr & 7)) << 3),
                  &sK[buf][(i * 4 + w) * 1024]);
    }
  };
  auto stageV = [&](int k0, int buf) {
#pragma unroll
    for (int i = 0; i < 2; ++i) {
      int c = i * 256 + c0;
      int d = c >> 3, ch = c & 7;
      gload_lds16(Vhead + (size_t)d * SS + k0 + ((ch ^ (d & 7)) << 3),
                  &sV[buf][(i * 4 + w) * 1024]);
    }
  };

  // ---- pass 1: per-row sumexp (max-free, clamped). lane q = lr, k = 4lg+r ----
  stageK(0, 0);
  asm volatile("s_waitcnt vmcnt(0)" ::: "memory");
  __builtin_amdgcn_s_barrier();

  float lsum = 0.0f;

  for (int t = 0; t < 32; ++t) {
    const int cur = t & 1;
    if (t < 31) stageK((t + 1) * 64, cur ^ 1);

    const uint32_t mw0 = mrow[2 * t], mw1 = mrow[2 * t + 1];
    const bool fast = ((mw0 & mw1) == 0xFFFFFFFFu);

#pragma unroll
    for (int sub = 0; sub < 4; ++sub) {
      const int kr = sub * 16 + lr;
      bf16x8 k0f = *(const bf16x8*)&sK[cur][kr * 128 + ((lg ^ (kr & 7)) << 4)];
      bf16x8 k1f = *(const bf16x8*)&sK[cur][kr * 128 + (((4 + lg) ^ (kr & 7)) << 4)];
      __builtin_amdgcn_s_setprio(1);
      f32x4 a = {};
      a = mfma16(k0f, qf0, a);
      a = mfma16(k1f, qf1, a);
      __builtin_amdgcn_s_setprio(0);
      if (!fast) {
        uint32_t bits = ((sub < 2) ? mw0 : mw1) >> ((sub & 1) * 16 + 4 * lg);
#pragma unroll
        for (int r = 0; r < 4; ++r) a[r] = ((bits >> r) & 1) ? a[r] : NBRAW;
      }
#pragma unroll
      for (int r = 0; r < 4; ++r)
        lsum += __builtin_amdgcn_exp2f(fminf(a[r] * C2, 80.0f));
    }
    asm volatile("s_waitcnt vmcnt(0)" ::: "memory");
    __builtin_amdgcn_s_barrier();
  }

  lsum += __shfl_xor(lsum, 16);
  lsum += __shfl_xor(lsum, 32);
  const float rl = 1.0f / lsum;

  f32x4 Oa[4] = {};
  float* pwbase = attnW + ((size_t)bh * SS + q0 + w * 16) * SS;

  // ---- pass 2: P(bf16) via LDS-transpose + 256B-run NT store + PV ----
  stageK(0, 0);
  stageV(0, 0);
  asm volatile("s_waitcnt vmcnt(0)" ::: "memory");
  __builtin_amdgcn_s_barrier();

  for (int t = 0; t < 32; ++t) {
    const int cur = t & 1;
    if (t < 31) { stageK((t + 1) * 64, cur ^ 1); stageV((t + 1) * 64, cur ^ 1); }

    const uint32_t mw0 = mrow[2 * t], mw1 = mrow[2 * t + 1];
    const bool fast = ((mw0 & mw1) == 0xFFFFFFFFu);

    // -- compute 4 sub-tiles (64 k-cols); lane holds P[q=lr][k=sub*16+4lg+r] --
#pragma unroll
    for (int sub = 0; sub < 4; ++sub) {
      const int kr = sub * 16 + lr;
      bf16x8 k0f = *(const bf16x8*)&sK[cur][kr * 128 + ((lg ^ (kr & 7)) << 4)];
      bf16x8 k1f = *(const bf16x8*)&sK[cur][kr * 128 + (((4 + lg) ^ (kr & 7)) << 4)];
      __builtin_amdgcn_s_setprio(1);
      f32x4 a = {};
      a = mfma16(k0f, qf0, a);
      a = mfma16(k1f, qf1, a);
      __builtin_amdgcn_s_setprio(0);
      if (!fast) {
        uint32_t bits = ((sub < 2) ? mw0 : mw1) >> ((sub & 1) * 16 + 4 * lg);
#pragma unroll
        for (int r = 0; r < 4; ++r) a[r] = ((bits >> r) & 1) ? a[r] : NBRAW;
      }
      bf16x4 pk;
#pragma unroll
      for (int r = 0; r < 4; ++r)
        pk[r] = (__bf16)(__builtin_amdgcn_exp2f(fminf(a[r] * C2, 80.0f)) * rl);
      const int cc = ((sub * 2 + (lg >> 1)) ^ (lr & 7));
      *(bf16x4*)((char*)&sPB[w][lr][0] + cc * 16 + (lg & 1) * 8) = pk;
    }

    // -- transposed NT store: 4 instrs x (4 rows x 256B contiguous runs) --
#pragma unroll
    for (int i = 0; i < 4; ++i) {
      const int row = i * 4 + (l >> 4);
      const int jj = l & 15;                 // 4 fp32 cols per lane
      const int cc = (jj >> 1) ^ (row & 7);
      bf16x4 pb = *(const bf16x4*)((const char*)&sPB[w][row][0] + cc * 16 + (jj & 1) * 8);
      f32x4 pv;
#pragma unroll
      for (int r = 0; r < 4; ++r) pv[r] = (float)pb[r];
      __builtin_nontemporal_store(pv,
          (f32x4*)(pwbase + (size_t)row * SS + t * 64 + jj * 4));
    }

    // -- PV: A-operand bf16x8 direct from sPB (chunk hh*4+lg ^ (lr&7)) --
#pragma unroll
    for (int hh = 0; hh < 2; ++hh) {
      bf16x8 pa = *(const bf16x8*)((const char*)&sPB[w][lr][0] +
                                   (((hh * 4 + lg) ^ (lr & 7)) * 16));
      __builtin_amdgcn_s_setprio(1);
#pragma unroll
      for (int dg = 0; dg < 4; ++dg) {
        const int d = dg * 16 + lr;
        bf16x8 vb = *(const bf16x8*)&sV[cur][d * 128 + (((hh * 4 + lg) ^ (d & 7)) << 4)];
        Oa[dg] = mfma16(pa, vb, Oa[dg]);
      }
      __builtin_amdgcn_s_setprio(0);
    }

    // counted drain: retire the 4 staging loads, leave the 4 NT stores in flight
    asm volatile("s_waitcnt vmcnt(4)" ::: "memory");
    __builtin_amdgcn_s_barrier();
  }

  // epilogue: context -> [b*s][h*64+d] bf16 (Oa: q = 4lg+r, d = dg*16+lr)
#pragma unroll
  for (int dg = 0; dg < 4; ++dg)
#pragma unroll
    for (int r = 0; r < 4; ++r)
      ctx[(size_t)(b * SS + q0 + w * 16 + 4 * lg + r) * DIMM + h * HD + dg * 16 + lr] =
          (__bf16)Oa[dg][r];
}

// ---------------- launch ----------------
extern "C" void kernel_launch(void* const* d_in, const int* in_sizes, int n_in,
                              void* d_out, int out_size, void* d_ws, size_t ws_size,
                              hipStream_t stream)
{
  const float* q   = (const float*)d_in[0];
  const float* k   = (const float*)d_in[1];
  const float* v   = (const float*)d_in[2];
  const int*   msk = (const int*)d_in[3];
  const float* Wq  = (const float*)d_in[4];
  const float* bq  = (const float*)d_in[5];
  const float* Wk  = (const float*)d_in[6];
  const float* bk  = (const float*)d_in[7];
  const float* Wv  = (const float*)d_in[8];
  const float* bv  = (const float*)d_in[9];
  const float* Wo  = (const float*)d_in[10];
  const float* bo  = (const float*)d_in[11];

  char* ws = (char*)d_ws;
  __bf16* xq  = (__bf16*)(ws);
  __bf16* xk  = (__bf16*)(ws + (8u << 20));
  __bf16* xv  = (__bf16*)(ws + (16u << 20));
  __bf16* wqb = (__bf16*)(ws + (24u << 20));
  __bf16* wkb = (__bf16*)(ws + (26u << 20));
  __bf16* wvb = (__bf16*)(ws + (28u << 20));
  __bf16* wob = (__bf16*)(ws + (30u << 20));
  __bf16* Qh  = (__bf16*)(ws + (32u << 20));
  __bf16* Kh  = (__bf16*)(ws + (40u << 20));
  __bf16* Vt  = (__bf16*)(ws + (48u << 20));
  __bf16* ctx = (__bf16*)(ws + (56u << 20));
  uint32_t* mbits = (uint32_t*)(ws + (64u << 20));

  CvtArgs ca;
  ca.src[0] = q;  ca.dst[0] = xq;  ca.n[0] = NTOK * DIMM;
  ca.src[1] = k;  ca.dst[1] = xk;  ca.n[1] = NTOK * DIMM;
  ca.src[2] = v;  ca.dst[2] = xv;  ca.n[2] = NTOK * DIMM;
  ca.src[3] = Wq; ca.dst[3] = wqb; ca.n[3] = DIMM * DIMM;
  ca.src[4] = Wk; ca.dst[4] = wkb; ca.n[4] = DIMM * DIMM;
  ca.src[5] = Wv; ca.dst[5] = wvb; ca.n[5] = DIMM * DIMM;
  ca.src[6] = Wo; ca.dst[6] = wob; ca.n[6] = DIMM * DIMM;
  cvt_kernel<<<dim3(2048, 7, 1), 256, 0, stream>>>(ca);
  maskbits_kernel<<<1, 128, 0, stream>>>(msk, mbits);

  GemmArgs g1;
  g1.A[0] = xq; g1.B[0] = wqb; g1.bias[0] = bq; g1.out[0] = (void*)Qh; g1.mode[0] = 0;
  g1.A[1] = xk; g1.B[1] = wkb; g1.bias[1] = bk; g1.out[1] = (void*)Kh; g1.mode[1] = 0;
  g1.A[2] = xv; g1.B[2] = wvb; g1.bias[2] = bv; g1.out[2] = (void*)Vt; g1.mode[2] = 1;
  gemm_bt<<<dim3(8, 32, 3), 256, 0, stream>>>(g1);

  float* out = (float*)d_out;
  float* attnW = out + (size_t)NTOK * DIMM;
  attn_kernel<<<dim3(1024, 1, 1), 256, 0, stream>>>(Qh, Kh, Vt, mbits, attnW, ctx);

  GemmArgs g2;
  g2.A[0] = ctx; g2.B[0] = wob; g2.bias[0] = bo; g2.out[0] = (void*)out; g2.mode[0] = 2;
  g2.A[1] = ctx; g2.B[1] = wob; g2.bias[1] = bo; g2.out[1] = (void*)out; g2.mode[1] = 2;
  g2.A[2] = ctx; g2.B[2] = wob; g2.bias[2] = bo; g2.out[2] = (void*)out; g2.mode[2] = 2;
  gemm_bt<<<dim3(8, 32, 1), 256, 0, stream>>>(g2);
}